// Round 1
// baseline (125.483 us; speedup 1.0000x reference)
//
#include <hip/hip_runtime.h>

// p/v trajectory double-scan, K = 2^23 elements of 3-vectors (fp32).
// v_i = v0 + c*S_i + (i+1)*g ; p_i = p0 + DT*(i+1)*v0 + DT*(c*T_i + tri*g) - 0.5*DT*(c*S_i + (i+1)*g)
// where y_k = f[max(k-1,0)], S = prefix(y), T = prefix(S), g=(0,0,-DT*G), tri=(i+1)(i+2)/2.

namespace {
constexpr int  KE    = 8388608;          // 2^23
constexpr int  CHUNK = 2048;             // elements per block
constexpr int  NB    = KE / CHUNK;       // 4096 blocks
constexpr int  BLOCK = 256;
constexpr int  R     = CHUNK / BLOCK;    // 8 elements per thread (raking)
constexpr int  PLANE = CHUNK + CHUNK / R + 1;  // 2305: +pad so phys(j)=j+(j>>3) is conflict-free, odd for plane stagger
constexpr float DTc = 0.01f;
constexpr float Cc  = 0.01f / 1.5f;      // DT/M
constexpr float GZ  = -0.01f * 9.81f;    // DT * (-G)
}

// ---------- Kernel A: per-block aggregates Sum_b, Ttot_b = sum_j (CHUNK-j)*y_j ----------
__global__ __launch_bounds__(BLOCK) void k_agg(const float* __restrict__ f,
                                               float* __restrict__ W) {
  const int b = blockIdx.x, t = threadIdx.x;
  const long start = (long)b * CHUNK;
  float s[3] = {0.f, 0.f, 0.f}, w[3] = {0.f, 0.f, 0.f};
  for (int j = t; j < CHUNK; j += BLOCK) {
    long m = start + j - 1; if (m < 0) m = 0;   // y_j = f[max(global-1,0)]
    const float wt = (float)(CHUNK - j);
#pragma unroll
    for (int q = 0; q < 3; ++q) {
      float v = f[3 * m + q];
      s[q] += v; w[q] += wt * v;
    }
  }
  __shared__ float red[6][BLOCK];
#pragma unroll
  for (int q = 0; q < 3; ++q) { red[q][t] = s[q]; red[3 + q][t] = w[q]; }
  __syncthreads();
  for (int st = BLOCK / 2; st > 0; st >>= 1) {
    if (t < st) {
#pragma unroll
      for (int q = 0; q < 6; ++q) red[q][t] += red[q][t + st];
    }
    __syncthreads();
  }
  if (t == 0) {
#pragma unroll
    for (int q = 0; q < 3; ++q) {
      W[q * NB + b]       = red[q][0];       // Sum_b
      W[(3 + q) * NB + b] = red[3 + q][0];   // Ttot_b
    }
  }
}

// ---------- Kernel C: per-block scan + epilogue ----------
__global__ __launch_bounds__(BLOCK) void k_scan(const float* __restrict__ f,
                                                const float* __restrict__ W,
                                                const float* __restrict__ p0v,
                                                const float* __restrict__ v0v,
                                                float* __restrict__ out) {
  const int b = blockIdx.x, t = threadIdx.x;
  const int lane = t & 63, wid = t >> 6;
  const long start = (long)b * CHUNK;

  __shared__ double smem_d[(3 * PLANE + 1) / 2];  // 27.7 KB, overlaid: fp64 reduce buf then fp32 y-planes
  float* sm = (float*)smem_d;
  __shared__ float wag[4][6];

  // ---- phase A: global exclusive (S_g, T_g) by order-independent weighted reduction over aggregates
  // T_g = CHUNK * sum_{c<b} (b-1-c)*Sum_c + sum_{c<b} Ttot_c ;  S_g = sum_{c<b} Sum_c
  double A1[3] = {0, 0, 0}, A2[3] = {0, 0, 0}, A3[3] = {0, 0, 0};
  for (int c = t; c < b; c += BLOCK) {
    double wd = (double)(b - 1 - c);
#pragma unroll
    for (int q = 0; q < 3; ++q) {
      double sv = (double)W[q * NB + c];
      A1[q] += sv; A2[q] += wd * sv; A3[q] += (double)W[(3 + q) * NB + c];
    }
  }
  {
    double* red = smem_d;
#pragma unroll
    for (int q = 0; q < 3; ++q) { red[t * 9 + q] = A1[q]; red[t * 9 + 3 + q] = A2[q]; red[t * 9 + 6 + q] = A3[q]; }
    __syncthreads();
    for (int st = BLOCK / 2; st > 0; st >>= 1) {
      if (t < st) {
#pragma unroll
        for (int q = 0; q < 9; ++q) red[t * 9 + q] += red[(t + st) * 9 + q];
      }
      __syncthreads();
    }
  }
  float Sg[3], Tg[3];
  {
    double* red = smem_d;
#pragma unroll
    for (int q = 0; q < 3; ++q) {
      Sg[q] = (float)red[q];
      Tg[q] = (float)((double)CHUNK * red[3 + q] + red[6 + q]);
    }
  }
  __syncthreads();  // before overwriting smem with y planes

  // ---- phase B: stage y into padded LDS planes (float4 global loads, de-interleave)
  {
    const float4* src = (const float4*)(f + 3 * start);  // 16B-aligned: 3*CHUNK*b floats
#pragma unroll
    for (int it = 0; it < (3 * CHUNK / 4) / BLOCK; ++it) {  // 6 iters
      int q4 = it * BLOCK + t;
      float4 d = src[q4];
      int s0 = 4 * q4;
      float vals[4] = {d.x, d.y, d.z, d.w};
#pragma unroll
      for (int r = 0; r < 4; ++r) {
        int s = s0 + r;
        int j = s / 3 + 1;            // f[start + s/3] supplies y_{s/3+1}
        int c = s - (j - 1) * 3;
        if (j < CHUNK) sm[c * PLANE + j + (j >> 3)] = vals[r];
      }
    }
    if (t == 0) {                     // y_0 = f[max(start-1,0)]
      long m = start - 1; if (m < 0) m = 0;
#pragma unroll
      for (int q = 0; q < 3; ++q) sm[q * PLANE + 0] = f[3 * m + q];
    }
  }
  __syncthreads();

  // ---- phase C: per-thread (Sum, Ttot) rake, then block scan with (S,T,L) composition
  const int j0 = t * R;
  float tS[3] = {0, 0, 0}, tT[3] = {0, 0, 0};
#pragma unroll
  for (int e = 0; e < R; ++e) {
    int j = j0 + e, ph = j + (j >> 3);
    float wt = (float)(R - e);
#pragma unroll
    for (int q = 0; q < 3; ++q) {
      float v = sm[q * PLANE + ph];
      tS[q] += v; tT[q] += wt * v;
    }
  }
  // Kogge-Stone inclusive scan over 64 lanes; op(A,B): T = T_A + L_B*S_A + T_B ; S = S_A+S_B ; L = L_A+L_B
  float L = (float)R;
#pragma unroll
  for (int d = 1; d < 64; d <<= 1) {
    float pL = __shfl_up(L, d);
    float pS[3], pT[3];
#pragma unroll
    for (int q = 0; q < 3; ++q) { pS[q] = __shfl_up(tS[q], d); pT[q] = __shfl_up(tT[q], d); }
    if (lane >= d) {
#pragma unroll
      for (int q = 0; q < 3; ++q) { tT[q] = pT[q] + L * pS[q] + tT[q]; tS[q] = pS[q] + tS[q]; }
      L += pL;
    }
  }
  // lane-exclusive within wave
  float eS[3], eT[3];
#pragma unroll
  for (int q = 0; q < 3; ++q) { eS[q] = __shfl_up(tS[q], 1); eT[q] = __shfl_up(tT[q], 1); }
  if (lane == 0) {
#pragma unroll
    for (int q = 0; q < 3; ++q) { eS[q] = 0.f; eT[q] = 0.f; }
  }
  // wave aggregates -> LDS, sequential combine over earlier waves (L_w = 512 elements)
  if (lane == 63) {
#pragma unroll
    for (int q = 0; q < 3; ++q) { wag[wid][q] = tS[q]; wag[wid][3 + q] = tT[q]; }
  }
  __syncthreads();
  float oS[3] = {0, 0, 0}, oT[3] = {0, 0, 0};
  for (int w = 0; w < wid; ++w) {
#pragma unroll
    for (int q = 0; q < 3; ++q) oT[q] = oT[q] + 512.0f * oS[q] + wag[w][3 + q];
#pragma unroll
    for (int q = 0; q < 3; ++q) oS[q] = oS[q] + wag[w][q];
  }
  // thread exclusive-in-block, then combine with global prefix
  float S1[3], T1[3];
  const float Lex = (float)(R * lane);
#pragma unroll
  for (int q = 0; q < 3; ++q) {
    float Sb = oS[q] + eS[q];
    float Tb = oT[q] + Lex * oS[q] + eT[q];
    S1[q] = Sg[q] + Sb;
    T1[q] = Tg[q] + (float)(R * t) * Sg[q] + Tb;
  }

  // ---- phase D: serial per-element scan + fused epilogue, float4 stores
  const float p0x = p0v[0], p0y = p0v[1], p0z = p0v[2];
  const float v0x = v0v[0], v0y = v0v[1], v0z = v0v[2];
  float pr[3 * R], vr[3 * R];
  float sr[3] = {0, 0, 0}, tr[3] = {0, 0, 0};
#pragma unroll
  for (int e = 0; e < R; ++e) {
    int j = j0 + e, ph = j + (j >> 3);
#pragma unroll
    for (int q = 0; q < 3; ++q) {
      float v = sm[q * PLANE + ph];
      sr[q] += v; tr[q] += sr[q];
    }
    long i = start + j;
    double n1d = (double)(i + 1);
    float n1  = (float)n1d;
    float tri = (float)(0.5 * n1d * (n1d + 1.0));
    float ep1 = (float)(e + 1);
    float S_[3], T_[3];
#pragma unroll
    for (int q = 0; q < 3; ++q) { S_[q] = S1[q] + sr[q]; T_[q] = T1[q] + ep1 * S1[q] + tr[q]; }
    float vx = v0x + Cc * S_[0];
    float vy = v0y + Cc * S_[1];
    float vz = v0z + Cc * S_[2] + GZ * n1;
    float px = p0x + DTc * n1 * v0x + DTc * Cc * T_[0] - 0.5f * DTc * Cc * S_[0];
    float py = p0y + DTc * n1 * v0y + DTc * Cc * T_[1] - 0.5f * DTc * Cc * S_[1];
    float pz = p0z + DTc * n1 * v0z + DTc * Cc * T_[2] - 0.5f * DTc * Cc * S_[2]
             + DTc * GZ * tri - 0.5f * DTc * GZ * n1;
    pr[3 * e] = px; pr[3 * e + 1] = py; pr[3 * e + 2] = pz;
    vr[3 * e] = vx; vr[3 * e + 1] = vy; vr[3 * e + 2] = vz;
  }
  {
    float4* pw = (float4*)(out + 3 * (start + j0));                 // p block
    float4* vw = (float4*)(out + (long)3 * KE + 3 * (start + j0));  // v block
#pragma unroll
    for (int q = 0; q < (3 * R) / 4; ++q) {
      pw[q] = make_float4(pr[4 * q], pr[4 * q + 1], pr[4 * q + 2], pr[4 * q + 3]);
      vw[q] = make_float4(vr[4 * q], vr[4 * q + 1], vr[4 * q + 2], vr[4 * q + 3]);
    }
  }
}

extern "C" void kernel_launch(void* const* d_in, const int* in_sizes, int n_in,
                              void* d_out, int out_size, void* d_ws, size_t ws_size,
                              hipStream_t stream) {
  const float* f  = (const float*)d_in[0];
  const float* p0 = (const float*)d_in[1];
  const float* v0 = (const float*)d_in[2];
  float* out = (float*)d_out;
  float* W   = (float*)d_ws;  // 6*NB floats = 96 KB of scratch
  k_agg <<<NB, BLOCK, 0, stream>>>(f, W);
  k_scan<<<NB, BLOCK, 0, stream>>>(f, W, p0, v0, out);
}